// Round 5
// baseline (704.235 us; speedup 1.0000x reference)
//
#include <hip/hip_runtime.h>
#include <stdint.h>

typedef unsigned short u16;
typedef __bf16 bf16x8 __attribute__((ext_vector_type(8), may_alias));
typedef float f32x4 __attribute__((ext_vector_type(4), may_alias));

typedef void __attribute__((address_space(1))) as1_void;
typedef void __attribute__((address_space(3))) as3_void;

#define MFMA16 __builtin_amdgcn_mfma_f32_16x16x32_bf16

__device__ __forceinline__ void async_copy16(const void* g, void* l) {
    __builtin_amdgcn_global_load_lds((as1_void*)g, (as3_void*)l, 16, 0, 0);
}

// LDS-only barrier: do NOT drain vmcnt — keeps register-staged global loads
// in flight across the sync (AITER-style pipeline).
__device__ __forceinline__ void barrier_lgkm() {
    asm volatile("s_waitcnt lgkmcnt(0)\n\ts_barrier" ::: "memory");
}

// round-to-nearest-even fp32 -> bf16 bits
__device__ __forceinline__ u16 f2bf(float f) {
    union { float f; unsigned u; } c; c.f = f;
    unsigned u = c.u;
    u += 0x7fffu + ((u >> 16) & 1u);
    return (u16)(u >> 16);
}

// ---------------- elementwise cast fp32 -> bf16 (vectorized x4, optional scale) --
__global__ __launch_bounds__(256) void cast_f32_bf16(
    const float* __restrict__ in, u16* __restrict__ out, int n4, float scale) {
    int i = blockIdx.x * 256 + threadIdx.x;
    if (i < n4) {
        f32x4 v = *(const f32x4*)&in[(size_t)i * 4];
        ushort4 o;
        o.x = f2bf(v[0] * scale); o.y = f2bf(v[1] * scale);
        o.z = f2bf(v[2] * scale); o.w = f2bf(v[3] * scale);
        *(ushort4*)&out[(size_t)i * 4] = o;
    }
}

// ---------------- tiled transpose + cast: in fp32 (R,C) -> out bf16 (C,R) -----
__global__ __launch_bounds__(256) void transpose_cast(
    const float* __restrict__ in, u16* __restrict__ out, int R, int C) {
    __shared__ float tile[64][65];
    const float* inb = in + (size_t)blockIdx.z * R * C;
    u16* outb = out + (size_t)blockIdx.z * R * C;
    int t = threadIdx.x;
    int c0 = blockIdx.x * 64, r0 = blockIdx.y * 64;
    int tr = t >> 4, tc = (t & 15) * 4;
#pragma unroll
    for (int p = 0; p < 4; ++p) {
        int r = tr + p * 16;
        f32x4 v = *(const f32x4*)&inb[(size_t)(r0 + r) * C + c0 + tc];
        tile[r][tc] = v[0]; tile[r][tc + 1] = v[1];
        tile[r][tc + 2] = v[2]; tile[r][tc + 3] = v[3];
    }
    __syncthreads();
    int wc = t >> 4, wr = (t & 15) * 4;
#pragma unroll
    for (int p = 0; p < 4; ++p) {
        int cl = wc + p * 16;
        ushort4 o;
        o.x = f2bf(tile[wr + 0][cl]); o.y = f2bf(tile[wr + 1][cl]);
        o.z = f2bf(tile[wr + 2][cl]); o.w = f2bf(tile[wr + 3][cl]);
        *(ushort4*)&outb[(size_t)(c0 + cl) * R + r0 + wr] = o;
    }
}

// ---------------- flash attention v3 (transposed dataflow, 2 q-tiles/wave) -----
__global__ __launch_bounds__(256) void flash_attn(
    const u16* __restrict__ Q, const u16* __restrict__ Kb,
    const u16* __restrict__ VT, const int* __restrict__ mask,
    u16* __restrict__ O) {
    __shared__ u16 kls[2][8192];   // K tile 128x64, fragment order, double-buffered
    __shared__ u16 vls[8192];      // V^T tile 64x128, fragment order
    __shared__ u16 pls[8][2048];   // per-wave x per-qtile P^T 16x128, XOR-swizzled

    const int bid = blockIdx.x;
    const int qt = bid & 15;
    const int h = (bid >> 4) & 15;
    const int n = bid >> 8;
    const int t = threadIdx.x;
    const int w = t >> 6, lane = t & 63;
    const int m16 = lane & 15, quad = lane >> 4;

    const size_t qrowA = (size_t)(n * 2048 + qt * 128 + w * 16 + m16);
    const size_t qrowB = qrowA + 64;
    bf16x8 qfA0 = *(const bf16x8*)&Q[qrowA * 1024 + h * 64 + quad * 8];
    bf16x8 qfA1 = *(const bf16x8*)&Q[qrowA * 1024 + h * 64 + 32 + quad * 8];
    bf16x8 qfB0 = *(const bf16x8*)&Q[qrowB * 1024 + h * 64 + quad * 8];
    bf16x8 qfB1 = *(const bf16x8*)&Q[qrowB * 1024 + h * 64 + 32 + quad * 8];

    const int* maskn = mask + n * 2048;
    int allones;
    {
        int ok = 1;
#pragma unroll
        for (int i = 0; i < 8; ++i) {
            int4 mv = *(const int4*)&maskn[lane * 32 + i * 4];
            ok &= (mv.x != 0) & (mv.y != 0) & (mv.z != 0) & (mv.w != 0);
        }
        allones = __all(ok);
    }

    f32x4 otA[4] = {}, otB[4] = {};
    f32x4 sumA = {}, sumB = {};

    const u16* Kbase = Kb + (size_t)(n * 2048) * 1024 + h * 64;
    const u16* Vbase = VT + (size_t)(n * 1024 + h * 64) * 2048;
    u16* pwA = &pls[w * 2][0];
    u16* pwB = &pls[w * 2 + 1][0];

#pragma unroll
    for (int i = 0; i < 4; ++i) {
        int e = w * 4 + i;
        async_copy16(&Kbase[(size_t)((e >> 1) * 16 + m16) * 1024 + (e & 1) * 32 + quad * 8],
                     &kls[0][e * 512]);
    }
    __syncthreads();

    for (int kt = 0; kt < 16; ++kt) {
        const u16* kcur = kls[kt & 1];
        if (kt + 1 < 16) {
            u16* knext = kls[(kt + 1) & 1];
#pragma unroll
            for (int i = 0; i < 4; ++i) {
                int e = w * 4 + i;
                async_copy16(&Kbase[(size_t)((kt + 1) * 128 + (e >> 1) * 16 + m16) * 1024 +
                                    (e & 1) * 32 + quad * 8], &knext[e * 512]);
            }
        }
#pragma unroll
        for (int i = 0; i < 4; ++i) {
            int e = w * 4 + i;
            async_copy16(&Vbase[(size_t)((e >> 2) * 16 + m16) * 2048 + kt * 128 +
                                (e & 3) * 32 + quad * 8], &vls[e * 512]);
        }

        f32x4 sA[8] = {}, sB[8] = {};
#pragma unroll
        for (int ct = 0; ct < 8; ++ct) {
            bf16x8 a0 = *(const bf16x8*)&kcur[(ct * 2 + 0) * 512 + lane * 8];
            bf16x8 a1 = *(const bf16x8*)&kcur[(ct * 2 + 1) * 512 + lane * 8];
            sA[ct] = MFMA16(a0, qfA0, sA[ct], 0, 0, 0);
            sA[ct] = MFMA16(a1, qfA1, sA[ct], 0, 0, 0);
            sB[ct] = MFMA16(a0, qfB0, sB[ct], 0, 0, 0);
            sB[ct] = MFMA16(a1, qfB1, sB[ct], 0, 0, 0);
        }

        if (allones) {
#pragma unroll
            for (int ct = 0; ct < 8; ++ct) {
                int c = ct * 2 + (quad >> 1);
                int off = m16 * 128 + (((c ^ m16) & 15) << 3) + (quad & 1) * 4;
                {
                    float p0 = __builtin_amdgcn_exp2f(sA[ct][0]);
                    float p1 = __builtin_amdgcn_exp2f(sA[ct][1]);
                    float p2 = __builtin_amdgcn_exp2f(sA[ct][2]);
                    float p3 = __builtin_amdgcn_exp2f(sA[ct][3]);
                    sumA[0] += p0; sumA[1] += p1; sumA[2] += p2; sumA[3] += p3;
                    unsigned lo = __builtin_amdgcn_perm(__float_as_uint(p1), __float_as_uint(p0), 0x07060302);
                    unsigned hi = __builtin_amdgcn_perm(__float_as_uint(p3), __float_as_uint(p2), 0x07060302);
                    *(uint2*)&pwA[off] = make_uint2(lo, hi);
                }
                {
                    float p0 = __builtin_amdgcn_exp2f(sB[ct][0]);
                    float p1 = __builtin_amdgcn_exp2f(sB[ct][1]);
                    float p2 = __builtin_amdgcn_exp2f(sB[ct][2]);
                    float p3 = __builtin_amdgcn_exp2f(sB[ct][3]);
                    sumB[0] += p0; sumB[1] += p1; sumB[2] += p2; sumB[3] += p3;
                    unsigned lo = __builtin_amdgcn_perm(__float_as_uint(p1), __float_as_uint(p0), 0x07060302);
                    unsigned hi = __builtin_amdgcn_perm(__float_as_uint(p3), __float_as_uint(p2), 0x07060302);
                    *(uint2*)&pwB[off] = make_uint2(lo, hi);
                }
            }
        } else {
#pragma unroll
            for (int ct = 0; ct < 8; ++ct) {
                const int4 mv = *(const int4*)&maskn[kt * 128 + ct * 16 + quad * 4];
                int c = ct * 2 + (quad >> 1);
                int off = m16 * 128 + (((c ^ m16) & 15) << 3) + (quad & 1) * 4;
                {
                    float p0 = __builtin_amdgcn_exp2f(sA[ct][0]) * (mv.x ? 1.f : 0.f);
                    float p1 = __builtin_amdgcn_exp2f(sA[ct][1]) * (mv.y ? 1.f : 0.f);
                    float p2 = __builtin_amdgcn_exp2f(sA[ct][2]) * (mv.z ? 1.f : 0.f);
                    float p3 = __builtin_amdgcn_exp2f(sA[ct][3]) * (mv.w ? 1.f : 0.f);
                    sumA[0] += p0; sumA[1] += p1; sumA[2] += p2; sumA[3] += p3;
                    unsigned lo = __builtin_amdgcn_perm(__float_as_uint(p1), __float_as_uint(p0), 0x07060302);
                    unsigned hi = __builtin_amdgcn_perm(__float_as_uint(p3), __float_as_uint(p2), 0x07060302);
                    *(uint2*)&pwA[off] = make_uint2(lo, hi);
                }
                {
                    float p0 = __builtin_amdgcn_exp2f(sB[ct][0]) * (mv.x ? 1.f : 0.f);
                    float p1 = __builtin_amdgcn_exp2f(sB[ct][1]) * (mv.y ? 1.f : 0.f);
                    float p2 = __builtin_amdgcn_exp2f(sB[ct][2]) * (mv.z ? 1.f : 0.f);
                    float p3 = __builtin_amdgcn_exp2f(sB[ct][3]) * (mv.w ? 1.f : 0.f);
                    sumB[0] += p0; sumB[1] += p1; sumB[2] += p2; sumB[3] += p3;
                    unsigned lo = __builtin_amdgcn_perm(__float_as_uint(p1), __float_as_uint(p0), 0x07060302);
                    unsigned hi = __builtin_amdgcn_perm(__float_as_uint(p3), __float_as_uint(p2), 0x07060302);
                    *(uint2*)&pwB[off] = make_uint2(lo, hi);
                }
            }
        }

        __syncthreads();   // V staged (vmcnt drained) + P writes ordered

        bf16x8 pfA[4], pfB[4];
#pragma unroll
        for (int kc2 = 0; kc2 < 4; ++kc2) {
            int off = m16 * 128 + ((((kc2 * 4 + quad) ^ m16) & 15) << 3);
            pfA[kc2] = *(const bf16x8*)&pwA[off];
            pfB[kc2] = *(const bf16x8*)&pwB[off];
        }
#pragma unroll
        for (int kc2 = 0; kc2 < 4; ++kc2) {
#pragma unroll
            for (int dt = 0; dt < 4; ++dt) {
                bf16x8 vf = *(const bf16x8*)&vls[(dt * 4 + kc2) * 512 + lane * 8];
                otA[dt] = MFMA16(vf, pfA[kc2], otA[dt], 0, 0, 0);
                otB[dt] = MFMA16(vf, pfB[kc2], otB[dt], 0, 0, 0);
            }
        }
        __syncthreads();
    }

    float lA = (sumA[0] + sumA[1]) + (sumA[2] + sumA[3]);
    float lB = (sumB[0] + sumB[1]) + (sumB[2] + sumB[3]);
    lA += __shfl_xor(lA, 16); lA += __shfl_xor(lA, 32);
    lB += __shfl_xor(lB, 16); lB += __shfl_xor(lB, 32);
    float invA = 1.f / fmaxf(lA, 1e-30f);
    float invB = 1.f / fmaxf(lB, 1e-30f);

    const size_t obA = qrowA * 1024 + h * 64;
    const size_t obB = qrowB * 1024 + h * 64;
#pragma unroll
    for (int dt = 0; dt < 4; ++dt) {
        unsigned lo = (unsigned)f2bf(otA[dt][0] * invA) | ((unsigned)f2bf(otA[dt][1] * invA) << 16);
        unsigned hi = (unsigned)f2bf(otA[dt][2] * invA) | ((unsigned)f2bf(otA[dt][3] * invA) << 16);
        *(uint2*)&O[obA + dt * 16 + quad * 4] = make_uint2(lo, hi);
        lo = (unsigned)f2bf(otB[dt][0] * invB) | ((unsigned)f2bf(otB[dt][1] * invB) << 16);
        hi = (unsigned)f2bf(otB[dt][2] * invB) | ((unsigned)f2bf(otB[dt][3] * invB) << 16);
        *(uint2*)&O[obB + dt * 16 + quad * 4] = make_uint2(lo, hi);
    }
}

// ---------------- bf16 GEMM v2: register-staged software pipeline ----------------
// C(M,N) = A(M,K) * Bt(N,K)^T + bias. BM x BN tile, BK=64, 4 waves 2x2.
// Pipeline: tile k+2 global->VGPR issued at iter k start; tile k+1 VGPR->LDS
// (ds_write) at iter k end (data ~2 iters old => vmcnt wait ~0); barriers are
// lgkmcnt-only so global loads stay in flight across them.
template <int BM, int BN, int RELU, int OUTBF>
__global__ __launch_bounds__(256) void gemm_bt(
    const u16* __restrict__ A, const u16* __restrict__ Bt,
    const float* __restrict__ bias, void* __restrict__ Cout,
    int M, int N, int K) {
    constexpr int MI = BM / 32;
    constexpr int NJ = BN / 32;
    constexpr int NLD = MI + NJ;
    __shared__ u16 sm[2][(BM + BN) * 64];
    const int lane = threadIdx.x & 63;
    const int w = threadIdx.x >> 6;
    const int m16 = lane & 15, quad = lane >> 4;
    const int nBn = N / BN;
    const int bm = blockIdx.x / nBn, bn = blockIdx.x % nBn;
    const int r2 = w >> 1, c2 = w & 1;

    const u16* Abase = A + (size_t)(bm * BM + m16) * K + quad * 8;
    const u16* Bbase = Bt + (size_t)(bn * BN + m16) * K + quad * 8;

    bf16x8 ld[2][NLD];

    auto gload = [&](int set, int k0) {
#pragma unroll
        for (int i = 0; i < MI; ++i) {
            int e = w * MI + i;
            ld[set][i] = *(const bf16x8*)&Abase[(size_t)((e >> 1) * 16) * K + k0 + (e & 1) * 32];
        }
#pragma unroll
        for (int i = 0; i < NJ; ++i) {
            int e = w * NJ + i;
            ld[set][MI + i] = *(const bf16x8*)&Bbase[(size_t)((e >> 1) * 16) * K + k0 + (e & 1) * 32];
        }
    };
    auto swrite = [&](int set, int buf) {
        u16* smA = &sm[buf][0];
        u16* smB = smA + BM * 64;
#pragma unroll
        for (int i = 0; i < MI; ++i) {
            int e = w * MI + i;
            *(bf16x8*)&smA[e * 512 + lane * 8] = ld[set][i];
        }
#pragma unroll
        for (int i = 0; i < NJ; ++i) {
            int e = w * NJ + i;
            *(bf16x8*)&smB[e * 512 + lane * 8] = ld[set][MI + i];
        }
    };

    f32x4 acc[MI][NJ] = {};
    const int nK = K >> 6;

    // prologue: tile0 -> regs -> LDS buf0; tile1 load stays in flight
    gload(0, 0);
    gload(1, 64);
    swrite(0, 0);          // compiler inserts partial vmcnt wait for set 0 only
    barrier_lgkm();

    for (int kt = 0; kt < nK; ++kt) {
        const int cur = kt & 1;
        if (kt + 2 < nK) gload(cur, (kt + 2) << 6);   // overwrites regs of tile kt (already in LDS)
        const u16* smA = &sm[cur][0];
        const u16* smB = smA + BM * 64;
#pragma unroll
        for (int kc = 0; kc < 2; ++kc) {
            bf16x8 a[MI], b[NJ];
#pragma unroll
            for (int i = 0; i < MI; ++i)
                a[i] = *(const bf16x8*)&smA[((r2 * MI + i) * 2 + kc) * 512 + lane * 8];
#pragma unroll
            for (int j = 0; j < NJ; ++j)
                b[j] = *(const bf16x8*)&smB[((c2 * NJ + j) * 2 + kc) * 512 + lane * 8];
#pragma unroll
            for (int i = 0; i < MI; ++i)
#pragma unroll
                for (int j = 0; j < NJ; ++j)
                    acc[i][j] = MFMA16(a[i], b[j], acc[i][j], 0, 0, 0);
        }
        if (kt + 1 < nK) {
            swrite(cur ^ 1, cur ^ 1);   // tile kt+1 (loaded ~2 iters ago) -> other buf
            barrier_lgkm();             // LDS-only drain; tile kt+2 loads stay in flight
        }
    }

    // epilogue: D row = quad*4 + reg, col = m16
    float bv[NJ];
#pragma unroll
    for (int j = 0; j < NJ; ++j)
        bv[j] = bias[bn * BN + c2 * (BN / 2) + j * 16 + m16];
#pragma unroll
    for (int i = 0; i < MI; ++i) {
        int row0 = bm * BM + r2 * (BM / 2) + i * 16 + quad * 4;
#pragma unroll
        for (int j = 0; j < NJ; ++j) {
            int col = bn * BN + c2 * (BN / 2) + j * 16 + m16;
#pragma unroll
            for (int r = 0; r < 4; ++r) {
                float v = acc[i][j][r] + bv[j];
                if (RELU) v = fmaxf(v, 0.f);
                size_t idx = (size_t)(row0 + r) * N + col;
                if (OUTBF) ((u16*)Cout)[idx] = f2bf(v);
                else ((float*)Cout)[idx] = v;
            }
        }
    }
}

// ---------------- residual + layernorm (row = 1024) ----------------
__global__ __launch_bounds__(256) void ln_residual(
    const float* __restrict__ x, const float* __restrict__ res,
    const float* __restrict__ g, const float* __restrict__ b,
    float* __restrict__ out_f32, u16* __restrict__ out_bf16) {
    __shared__ float smr[8];
    int row = blockIdx.x;
    int t = threadIdx.x;
    f32x4 xv = *(const f32x4*)&x[(size_t)row * 1024 + t * 4];
    f32x4 rv = *(const f32x4*)&res[(size_t)row * 1024 + t * 4];
    xv += rv;
    float s = xv[0] + xv[1] + xv[2] + xv[3];
    float ss = xv[0] * xv[0] + xv[1] * xv[1] + xv[2] * xv[2] + xv[3] * xv[3];
#pragma unroll
    for (int d = 1; d < 64; d <<= 1) {
        s += __shfl_xor(s, d);
        ss += __shfl_xor(ss, d);
    }
    int w = t >> 6, lane = t & 63;
    if (lane == 0) { smr[w] = s; smr[4 + w] = ss; }
    __syncthreads();
    s = smr[0] + smr[1] + smr[2] + smr[3];
    ss = smr[4] + smr[5] + smr[6] + smr[7];
    float mu = s * (1.f / 1024.f);
    float var = ss * (1.f / 1024.f) - mu * mu;
    float rs = rsqrtf(var + 1e-5f);
    f32x4 gv = *(const f32x4*)&g[t * 4];
    f32x4 bv = *(const f32x4*)&b[t * 4];
    f32x4 y;
#pragma unroll
    for (int i = 0; i < 4; ++i) y[i] = (xv[i] - mu) * rs * gv[i] + bv[i];
    *(f32x4*)&out_f32[(size_t)row * 1024 + t * 4] = y;
    if (out_bf16) {
        ushort4 o;
        o.x = f2bf(y[0]); o.y = f2bf(y[1]); o.z = f2bf(y[2]); o.w = f2bf(y[3]);
        *(ushort4*)&out_bf16[(size_t)row * 1024 + t * 4] = o;
    }
}

extern "C" void kernel_launch(void* const* d_in, const int* in_sizes, int n_in,
                              void* d_out, int out_size, void* d_ws, size_t ws_size,
                              hipStream_t stream) {
    const float* q = (const float*)d_in[0];
    const float* k = (const float*)d_in[1];
    const float* v = (const float*)d_in[2];
    const int* mask = (const int*)d_in[3];
    const float* fc_b = (const float*)d_in[5];
    const float* ln1_g = (const float*)d_in[6];
    const float* ln1_b = (const float*)d_in[7];
    const float* ff_b1 = (const float*)d_in[9];
    const float* ff_b2 = (const float*)d_in[11];
    const float* ln2_g = (const float*)d_in[12];
    const float* ln2_b = (const float*)d_in[13];
    const float* fc_w = (const float*)d_in[4];
    const float* ff_w1 = (const float*)d_in[8];
    const float* ff_w2 = (const float*)d_in[10];

    char* ws = (char*)d_ws;
    const size_t MB = 1024 * 1024;
    u16* qbf = (u16*)(ws + 0);          // 8 MB (pre-scaled by softmax scale*log2e)
    u16* kbf = (u16*)(ws + 8 * MB);     // 8 MB
    u16* vT  = (u16*)(ws + 16 * MB);    // 8 MB  (n, 1024, 2048)
    u16* ao  = (u16*)(ws + 24 * MB);    // 8 MB  attention out bf16
    u16* hbuf = (u16*)(ws + 0);         // 32 MB (reuses 0..32MB after attention+fc)
    u16* fcwT = (u16*)(ws + 32 * MB);   // 2 MB
    u16* w1T  = (u16*)(ws + 34 * MB);   // 8 MB
    u16* w2T  = (u16*)(ws + 42 * MB);   // 8 MB
    float* attn_raw = (float*)(ws + 50 * MB); // 16 MB
    float* fc_raw   = (float*)(ws + 50 * MB); // reuse (attn_raw dead after LN1)
    float* x1   = (float*)(ws + 66 * MB);     // 16 MB
    u16* x1bf   = (u16*)(ws + 82 * MB);       // 8 MB  (total 90 MB)

    const float k2 = 0.03125f * 1.44269504088896340736f; // 1/sqrt(1024) * log2(e)

    // preprocessing: casts + transposes (bf16, B^T layouts)
    cast_f32_bf16<<<4096, 256, 0, stream>>>(q, qbf, 1048576, k2);
    cast_f32_bf16<<<4096, 256, 0, stream>>>(k, kbf, 1048576, 1.0f);
    transpose_cast<<<dim3(16, 32, 2), 256, 0, stream>>>(v, vT, 2048, 1024);
    transpose_cast<<<dim3(16, 16, 1), 256, 0, stream>>>(fc_w, fcwT, 1024, 1024);
    transpose_cast<<<dim3(64, 16, 1), 256, 0, stream>>>(ff_w1, w1T, 1024, 4096);
    transpose_cast<<<dim3(16, 64, 1), 256, 0, stream>>>(ff_w2, w2T, 4096, 1024);

    // attention (grid 512: 128 q-rows per block, exactly 2 blocks/CU)
    flash_attn<<<512, 256, 0, stream>>>(qbf, kbf, vT, mask, ao);

    // out-proj + LN1  (64x128 tiles -> grid 512 = 2 blocks/CU)
    gemm_bt<64, 128, 0, 0><<<64 * 8, 256, 0, stream>>>(ao, fcwT, fc_b, attn_raw, 4096, 1024, 1024);
    ln_residual<<<4096, 256, 0, stream>>>(attn_raw, q, ln1_g, ln1_b, x1, x1bf);

    // FFN + LN2
    gemm_bt<128, 128, 1, 1><<<32 * 32, 256, 0, stream>>>(x1bf, w1T, ff_b1, hbuf, 4096, 4096, 1024);
    gemm_bt<64, 128, 0, 0><<<64 * 8, 256, 0, stream>>>(hbuf, w2T, ff_b2, fc_raw, 4096, 1024, 4096);
    ln_residual<<<4096, 256, 0, stream>>>(fc_raw, x1, ln2_g, ln2_b, (float*)d_out, (u16*)nullptr);
}

// Round 6
// 441.529 us; speedup vs baseline: 1.5950x; 1.5950x over previous
//
#include <hip/hip_runtime.h>
#include <stdint.h>

typedef unsigned short u16;
typedef __bf16 bf16x8 __attribute__((ext_vector_type(8), may_alias));
typedef float f32x4 __attribute__((ext_vector_type(4), may_alias));

typedef void __attribute__((address_space(1))) as1_void;
typedef void __attribute__((address_space(3))) as3_void;

#define MFMA16 __builtin_amdgcn_mfma_f32_16x16x32_bf16

__device__ __forceinline__ void async_copy16(const void* g, void* l) {
    __builtin_amdgcn_global_load_lds((as1_void*)g, (as3_void*)l, 16, 0, 0);
}

// LDS-only barrier: do NOT drain vmcnt — keeps register-staged global loads
// in flight across the sync (AITER-style pipeline).
__device__ __forceinline__ void barrier_lgkm() {
    asm volatile("s_waitcnt lgkmcnt(0)\n\ts_barrier" ::: "memory");
}

// round-to-nearest-even fp32 -> bf16 bits
__device__ __forceinline__ u16 f2bf(float f) {
    union { float f; unsigned u; } c; c.f = f;
    unsigned u = c.u;
    u += 0x7fffu + ((u >> 16) & 1u);
    return (u16)(u >> 16);
}

// ---------------- elementwise cast fp32 -> bf16 (vectorized x4, optional scale) --
__global__ __launch_bounds__(256) void cast_f32_bf16(
    const float* __restrict__ in, u16* __restrict__ out, int n4, float scale) {
    int i = blockIdx.x * 256 + threadIdx.x;
    if (i < n4) {
        f32x4 v = *(const f32x4*)&in[(size_t)i * 4];
        ushort4 o;
        o.x = f2bf(v[0] * scale); o.y = f2bf(v[1] * scale);
        o.z = f2bf(v[2] * scale); o.w = f2bf(v[3] * scale);
        *(ushort4*)&out[(size_t)i * 4] = o;
    }
}

// ---------------- tiled transpose + cast: in fp32 (R,C) -> out bf16 (C,R) -----
__global__ __launch_bounds__(256) void transpose_cast(
    const float* __restrict__ in, u16* __restrict__ out, int R, int C) {
    __shared__ float tile[64][65];
    const float* inb = in + (size_t)blockIdx.z * R * C;
    u16* outb = out + (size_t)blockIdx.z * R * C;
    int t = threadIdx.x;
    int c0 = blockIdx.x * 64, r0 = blockIdx.y * 64;
    int tr = t >> 4, tc = (t & 15) * 4;
#pragma unroll
    for (int p = 0; p < 4; ++p) {
        int r = tr + p * 16;
        f32x4 v = *(const f32x4*)&inb[(size_t)(r0 + r) * C + c0 + tc];
        tile[r][tc] = v[0]; tile[r][tc + 1] = v[1];
        tile[r][tc + 2] = v[2]; tile[r][tc + 3] = v[3];
    }
    __syncthreads();
    int wc = t >> 4, wr = (t & 15) * 4;
#pragma unroll
    for (int p = 0; p < 4; ++p) {
        int cl = wc + p * 16;
        ushort4 o;
        o.x = f2bf(tile[wr + 0][cl]); o.y = f2bf(tile[wr + 1][cl]);
        o.z = f2bf(tile[wr + 2][cl]); o.w = f2bf(tile[wr + 3][cl]);
        *(ushort4*)&outb[(size_t)(c0 + cl) * R + r0 + wr] = o;
    }
}

// ---------------- flash attention v3 (transposed dataflow, 2 q-tiles/wave) -----
__global__ __launch_bounds__(256) void flash_attn(
    const u16* __restrict__ Q, const u16* __restrict__ Kb,
    const u16* __restrict__ VT, const int* __restrict__ mask,
    u16* __restrict__ O) {
    __shared__ u16 kls[2][8192];   // K tile 128x64, fragment order, double-buffered
    __shared__ u16 vls[8192];      // V^T tile 64x128, fragment order
    __shared__ u16 pls[8][2048];   // per-wave x per-qtile P^T 16x128, XOR-swizzled

    const int bid = blockIdx.x;
    const int qt = bid & 15;
    const int h = (bid >> 4) & 15;
    const int n = bid >> 8;
    const int t = threadIdx.x;
    const int w = t >> 6, lane = t & 63;
    const int m16 = lane & 15, quad = lane >> 4;

    const size_t qrowA = (size_t)(n * 2048 + qt * 128 + w * 16 + m16);
    const size_t qrowB = qrowA + 64;
    bf16x8 qfA0 = *(const bf16x8*)&Q[qrowA * 1024 + h * 64 + quad * 8];
    bf16x8 qfA1 = *(const bf16x8*)&Q[qrowA * 1024 + h * 64 + 32 + quad * 8];
    bf16x8 qfB0 = *(const bf16x8*)&Q[qrowB * 1024 + h * 64 + quad * 8];
    bf16x8 qfB1 = *(const bf16x8*)&Q[qrowB * 1024 + h * 64 + 32 + quad * 8];

    const int* maskn = mask + n * 2048;
    int allones;
    {
        int ok = 1;
#pragma unroll
        for (int i = 0; i < 8; ++i) {
            int4 mv = *(const int4*)&maskn[lane * 32 + i * 4];
            ok &= (mv.x != 0) & (mv.y != 0) & (mv.z != 0) & (mv.w != 0);
        }
        allones = __all(ok);
    }

    f32x4 otA[4] = {}, otB[4] = {};
    f32x4 sumA = {}, sumB = {};

    const u16* Kbase = Kb + (size_t)(n * 2048) * 1024 + h * 64;
    const u16* Vbase = VT + (size_t)(n * 1024 + h * 64) * 2048;
    u16* pwA = &pls[w * 2][0];
    u16* pwB = &pls[w * 2 + 1][0];

#pragma unroll
    for (int i = 0; i < 4; ++i) {
        int e = w * 4 + i;
        async_copy16(&Kbase[(size_t)((e >> 1) * 16 + m16) * 1024 + (e & 1) * 32 + quad * 8],
                     &kls[0][e * 512]);
    }
    __syncthreads();

    for (int kt = 0; kt < 16; ++kt) {
        const u16* kcur = kls[kt & 1];
        if (kt + 1 < 16) {
            u16* knext = kls[(kt + 1) & 1];
#pragma unroll
            for (int i = 0; i < 4; ++i) {
                int e = w * 4 + i;
                async_copy16(&Kbase[(size_t)((kt + 1) * 128 + (e >> 1) * 16 + m16) * 1024 +
                                    (e & 1) * 32 + quad * 8], &knext[e * 512]);
            }
        }
#pragma unroll
        for (int i = 0; i < 4; ++i) {
            int e = w * 4 + i;
            async_copy16(&Vbase[(size_t)((e >> 2) * 16 + m16) * 2048 + kt * 128 +
                                (e & 3) * 32 + quad * 8], &vls[e * 512]);
        }

        f32x4 sA[8] = {}, sB[8] = {};
#pragma unroll
        for (int ct = 0; ct < 8; ++ct) {
            bf16x8 a0 = *(const bf16x8*)&kcur[(ct * 2 + 0) * 512 + lane * 8];
            bf16x8 a1 = *(const bf16x8*)&kcur[(ct * 2 + 1) * 512 + lane * 8];
            sA[ct] = MFMA16(a0, qfA0, sA[ct], 0, 0, 0);
            sA[ct] = MFMA16(a1, qfA1, sA[ct], 0, 0, 0);
            sB[ct] = MFMA16(a0, qfB0, sB[ct], 0, 0, 0);
            sB[ct] = MFMA16(a1, qfB1, sB[ct], 0, 0, 0);
        }

        if (allones) {
#pragma unroll
            for (int ct = 0; ct < 8; ++ct) {
                int c = ct * 2 + (quad >> 1);
                int off = m16 * 128 + (((c ^ m16) & 15) << 3) + (quad & 1) * 4;
                {
                    float p0 = __builtin_amdgcn_exp2f(sA[ct][0]);
                    float p1 = __builtin_amdgcn_exp2f(sA[ct][1]);
                    float p2 = __builtin_amdgcn_exp2f(sA[ct][2]);
                    float p3 = __builtin_amdgcn_exp2f(sA[ct][3]);
                    sumA[0] += p0; sumA[1] += p1; sumA[2] += p2; sumA[3] += p3;
                    unsigned lo = __builtin_amdgcn_perm(__float_as_uint(p1), __float_as_uint(p0), 0x07060302);
                    unsigned hi = __builtin_amdgcn_perm(__float_as_uint(p3), __float_as_uint(p2), 0x07060302);
                    *(uint2*)&pwA[off] = make_uint2(lo, hi);
                }
                {
                    float p0 = __builtin_amdgcn_exp2f(sB[ct][0]);
                    float p1 = __builtin_amdgcn_exp2f(sB[ct][1]);
                    float p2 = __builtin_amdgcn_exp2f(sB[ct][2]);
                    float p3 = __builtin_amdgcn_exp2f(sB[ct][3]);
                    sumB[0] += p0; sumB[1] += p1; sumB[2] += p2; sumB[3] += p3;
                    unsigned lo = __builtin_amdgcn_perm(__float_as_uint(p1), __float_as_uint(p0), 0x07060302);
                    unsigned hi = __builtin_amdgcn_perm(__float_as_uint(p3), __float_as_uint(p2), 0x07060302);
                    *(uint2*)&pwB[off] = make_uint2(lo, hi);
                }
            }
        } else {
#pragma unroll
            for (int ct = 0; ct < 8; ++ct) {
                const int4 mv = *(const int4*)&maskn[kt * 128 + ct * 16 + quad * 4];
                int c = ct * 2 + (quad >> 1);
                int off = m16 * 128 + (((c ^ m16) & 15) << 3) + (quad & 1) * 4;
                {
                    float p0 = __builtin_amdgcn_exp2f(sA[ct][0]) * (mv.x ? 1.f : 0.f);
                    float p1 = __builtin_amdgcn_exp2f(sA[ct][1]) * (mv.y ? 1.f : 0.f);
                    float p2 = __builtin_amdgcn_exp2f(sA[ct][2]) * (mv.z ? 1.f : 0.f);
                    float p3 = __builtin_amdgcn_exp2f(sA[ct][3]) * (mv.w ? 1.f : 0.f);
                    sumA[0] += p0; sumA[1] += p1; sumA[2] += p2; sumA[3] += p3;
                    unsigned lo = __builtin_amdgcn_perm(__float_as_uint(p1), __float_as_uint(p0), 0x07060302);
                    unsigned hi = __builtin_amdgcn_perm(__float_as_uint(p3), __float_as_uint(p2), 0x07060302);
                    *(uint2*)&pwA[off] = make_uint2(lo, hi);
                }
                {
                    float p0 = __builtin_amdgcn_exp2f(sB[ct][0]) * (mv.x ? 1.f : 0.f);
                    float p1 = __builtin_amdgcn_exp2f(sB[ct][1]) * (mv.y ? 1.f : 0.f);
                    float p2 = __builtin_amdgcn_exp2f(sB[ct][2]) * (mv.z ? 1.f : 0.f);
                    float p3 = __builtin_amdgcn_exp2f(sB[ct][3]) * (mv.w ? 1.f : 0.f);
                    sumB[0] += p0; sumB[1] += p1; sumB[2] += p2; sumB[3] += p3;
                    unsigned lo = __builtin_amdgcn_perm(__float_as_uint(p1), __float_as_uint(p0), 0x07060302);
                    unsigned hi = __builtin_amdgcn_perm(__float_as_uint(p3), __float_as_uint(p2), 0x07060302);
                    *(uint2*)&pwB[off] = make_uint2(lo, hi);
                }
            }
        }

        __syncthreads();   // V staged (vmcnt drained) + P writes ordered

        bf16x8 pfA[4], pfB[4];
#pragma unroll
        for (int kc2 = 0; kc2 < 4; ++kc2) {
            int off = m16 * 128 + ((((kc2 * 4 + quad) ^ m16) & 15) << 3);
            pfA[kc2] = *(const bf16x8*)&pwA[off];
            pfB[kc2] = *(const bf16x8*)&pwB[off];
        }
#pragma unroll
        for (int kc2 = 0; kc2 < 4; ++kc2) {
#pragma unroll
            for (int dt = 0; dt < 4; ++dt) {
                bf16x8 vf = *(const bf16x8*)&vls[(dt * 4 + kc2) * 512 + lane * 8];
                otA[dt] = MFMA16(vf, pfA[kc2], otA[dt], 0, 0, 0);
                otB[dt] = MFMA16(vf, pfB[kc2], otB[dt], 0, 0, 0);
            }
        }
        __syncthreads();
    }

    float lA = (sumA[0] + sumA[1]) + (sumA[2] + sumA[3]);
    float lB = (sumB[0] + sumB[1]) + (sumB[2] + sumB[3]);
    lA += __shfl_xor(lA, 16); lA += __shfl_xor(lA, 32);
    lB += __shfl_xor(lB, 16); lB += __shfl_xor(lB, 32);
    float invA = 1.f / fmaxf(lA, 1e-30f);
    float invB = 1.f / fmaxf(lB, 1e-30f);

    const size_t obA = qrowA * 1024 + h * 64;
    const size_t obB = qrowB * 1024 + h * 64;
#pragma unroll
    for (int dt = 0; dt < 4; ++dt) {
        unsigned lo = (unsigned)f2bf(otA[dt][0] * invA) | ((unsigned)f2bf(otA[dt][1] * invA) << 16);
        unsigned hi = (unsigned)f2bf(otA[dt][2] * invA) | ((unsigned)f2bf(otA[dt][3] * invA) << 16);
        *(uint2*)&O[obA + dt * 16 + quad * 4] = make_uint2(lo, hi);
        lo = (unsigned)f2bf(otB[dt][0] * invB) | ((unsigned)f2bf(otB[dt][1] * invB) << 16);
        hi = (unsigned)f2bf(otB[dt][2] * invB) | ((unsigned)f2bf(otB[dt][3] * invB) << 16);
        *(uint2*)&O[obB + dt * 16 + quad * 4] = make_uint2(lo, hi);
    }
}

// ---------------- bf16 GEMM v3: register-staged pipeline, STATIC buffer indices --
// C(M,N) = A(M,K) * Bt(N,K)^T + bias. BM x BN tile, BK=64, 4 waves 2x2.
// K-loop unrolled x2 so every ld-set / LDS-buf index is compile-time constant
// (runtime indices sent the staging regs to scratch in R5: 712 MB WRITE_SIZE).
// Pipeline: tile k+2 global->VGPR at iter k start; tile k+1 VGPR->LDS at iter k
// end (loaded ~2 iters ago => vmcnt wait ~0); lgkm-only barriers keep global
// loads in flight across the sync.
template <int BM, int BN, int RELU, int OUTBF>
__global__ __launch_bounds__(256) void gemm_bt(
    const u16* __restrict__ A, const u16* __restrict__ Bt,
    const float* __restrict__ bias, void* __restrict__ Cout,
    int M, int N, int K) {
    constexpr int MI = BM / 32;
    constexpr int NJ = BN / 32;
    constexpr int NLD = MI + NJ;
    __shared__ u16 sm[2][(BM + BN) * 64];
    const int lane = threadIdx.x & 63;
    const int w = threadIdx.x >> 6;
    const int m16 = lane & 15, quad = lane >> 4;
    const int nBn = N / BN;
    const int bm = blockIdx.x / nBn, bn = blockIdx.x % nBn;
    const int r2 = w >> 1, c2 = w & 1;

    const u16* Abase = A + (size_t)(bm * BM + m16) * K + quad * 8;
    const u16* Bbase = Bt + (size_t)(bn * BN + m16) * K + quad * 8;

    bf16x8 ld0[NLD], ld1[NLD];   // two separate statically-indexed sets

#define GLOAD(LD, k0)                                                                   \
    {                                                                                   \
        _Pragma("unroll") for (int i = 0; i < MI; ++i) {                                \
            int e = w * MI + i;                                                         \
            LD[i] = *(const bf16x8*)&Abase[(size_t)((e >> 1) * 16) * K + (k0) + (e & 1) * 32]; \
        }                                                                               \
        _Pragma("unroll") for (int i = 0; i < NJ; ++i) {                                \
            int e = w * NJ + i;                                                         \
            LD[MI + i] = *(const bf16x8*)&Bbase[(size_t)((e >> 1) * 16) * K + (k0) + (e & 1) * 32]; \
        }                                                                               \
    }
#define SWRITE(LD, buf)                                                                 \
    {                                                                                   \
        u16* smA_ = &sm[buf][0];                                                        \
        u16* smB_ = smA_ + BM * 64;                                                     \
        _Pragma("unroll") for (int i = 0; i < MI; ++i)                                  \
            *(bf16x8*)&smA_[(w * MI + i) * 512 + lane * 8] = LD[i];                     \
        _Pragma("unroll") for (int i = 0; i < NJ; ++i)                                  \
            *(bf16x8*)&smB_[(w * NJ + i) * 512 + lane * 8] = LD[MI + i];                \
    }
#define COMPUTE(buf)                                                                    \
    {                                                                                   \
        const u16* smA_ = &sm[buf][0];                                                  \
        const u16* smB_ = smA_ + BM * 64;                                               \
        _Pragma("unroll") for (int kc = 0; kc < 2; ++kc) {                              \
            bf16x8 a[MI], b[NJ];                                                        \
            _Pragma("unroll") for (int i = 0; i < MI; ++i)                              \
                a[i] = *(const bf16x8*)&smA_[((r2 * MI + i) * 2 + kc) * 512 + lane * 8];\
            _Pragma("unroll") for (int j = 0; j < NJ; ++j)                              \
                b[j] = *(const bf16x8*)&smB_[((c2 * NJ + j) * 2 + kc) * 512 + lane * 8];\
            _Pragma("unroll") for (int i = 0; i < MI; ++i)                              \
                _Pragma("unroll") for (int j = 0; j < NJ; ++j)                          \
                    acc[i][j] = MFMA16(a[i], b[j], acc[i][j], 0, 0, 0);                 \
        }                                                                               \
    }

    f32x4 acc[MI][NJ] = {};
    const int nK = K >> 6;   // always even here (16 or 64)

    // prologue: tile0 -> ld0 -> LDS buf0; tile1 -> ld1 (stays in flight)
    GLOAD(ld0, 0);
    GLOAD(ld1, 64);
    SWRITE(ld0, 0);      // compiler inserts partial vmcnt wait covering ld0 only
    barrier_lgkm();

    for (int kt = 0; kt < nK; kt += 2) {
        // even iter: compute buf0; refill ld0 with tile kt+2; stage ld1 -> buf1
        if (kt + 2 < nK) GLOAD(ld0, (kt + 2) << 6);
        COMPUTE(0);
        if (kt + 1 < nK) {
            SWRITE(ld1, 1);
            barrier_lgkm();
        }
        // odd iter: compute buf1; refill ld1 with tile kt+3; stage ld0 -> buf0
        if (kt + 3 < nK) GLOAD(ld1, (kt + 3) << 6);
        if (kt + 1 < nK) COMPUTE(1);
        if (kt + 2 < nK) {
            SWRITE(ld0, 0);
            barrier_lgkm();
        }
    }
#undef GLOAD
#undef SWRITE
#undef COMPUTE

    // epilogue: D row = quad*4 + reg, col = m16
    float bv[NJ];
#pragma unroll
    for (int j = 0; j < NJ; ++j)
        bv[j] = bias[bn * BN + c2 * (BN / 2) + j * 16 + m16];
#pragma unroll
    for (int i = 0; i < MI; ++i) {
        int row0 = bm * BM + r2 * (BM / 2) + i * 16 + quad * 4;
#pragma unroll
        for (int j = 0; j < NJ; ++j) {
            int col = bn * BN + c2 * (BN / 2) + j * 16 + m16;
#pragma unroll
            for (int r = 0; r < 4; ++r) {
                float v = acc[i][j][r] + bv[j];
                if (RELU) v = fmaxf(v, 0.f);
                size_t idx = (size_t)(row0 + r) * N + col;
                if (OUTBF) ((u16*)Cout)[idx] = f2bf(v);
                else ((float*)Cout)[idx] = v;
            }
        }
    }
}

// ---------------- residual + layernorm (row = 1024) ----------------
__global__ __launch_bounds__(256) void ln_residual(
    const float* __restrict__ x, const float* __restrict__ res,
    const float* __restrict__ g, const float* __restrict__ b,
    float* __restrict__ out_f32, u16* __restrict__ out_bf16) {
    __shared__ float smr[8];
    int row = blockIdx.x;
    int t = threadIdx.x;
    f32x4 xv = *(const f32x4*)&x[(size_t)row * 1024 + t * 4];
    f32x4 rv = *(const f32x4*)&res[(size_t)row * 1024 + t * 4];
    xv += rv;
    float s = xv[0] + xv[1] + xv[2] + xv[3];
    float ss = xv[0] * xv[0] + xv[1] * xv[1] + xv[2] * xv[2] + xv[3] * xv[3];
#pragma unroll
    for (int d = 1; d < 64; d <<= 1) {
        s += __shfl_xor(s, d);
        ss += __shfl_xor(ss, d);
    }
    int w = t >> 6, lane = t & 63;
    if (lane == 0) { smr[w] = s; smr[4 + w] = ss; }
    __syncthreads();
    s = smr[0] + smr[1] + smr[2] + smr[3];
    ss = smr[4] + smr[5] + smr[6] + smr[7];
    float mu = s * (1.f / 1024.f);
    float var = ss * (1.f / 1024.f) - mu * mu;
    float rs = rsqrtf(var + 1e-5f);
    f32x4 gv = *(const f32x4*)&g[t * 4];
    f32x4 bv = *(const f32x4*)&b[t * 4];
    f32x4 y;
#pragma unroll
    for (int i = 0; i < 4; ++i) y[i] = (xv[i] - mu) * rs * gv[i] + bv[i];
    *(f32x4*)&out_f32[(size_t)row * 1024 + t * 4] = y;
    if (out_bf16) {
        ushort4 o;
        o.x = f2bf(y[0]); o.y = f2bf(y[1]); o.z = f2bf(y[2]); o.w = f2bf(y[3]);
        *(ushort4*)&out_bf16[(size_t)row * 1024 + t * 4] = o;
    }
}

extern "C" void kernel_launch(void* const* d_in, const int* in_sizes, int n_in,
                              void* d_out, int out_size, void* d_ws, size_t ws_size,
                              hipStream_t stream) {
    const float* q = (const float*)d_in[0];
    const float* k = (const float*)d_in[1];
    const float* v = (const float*)d_in[2];
    const int* mask = (const int*)d_in[3];
    const float* fc_b = (const float*)d_in[5];
    const float* ln1_g = (const float*)d_in[6];
    const float* ln1_b = (const float*)d_in[7];
    const float* ff_b1 = (const float*)d_in[9];
    const float* ff_b2 = (const float*)d_in[11];
    const float* ln2_g = (const float*)d_in[12];
    const float* ln2_b = (const float*)d_in[13];
    const float* fc_w = (const float*)d_in[4];
    const float* ff_w1 = (const float*)d_in[8];
    const float* ff_w2 = (const float*)d_in[10];

    char* ws = (char*)d_ws;
    const size_t MB = 1024 * 1024;
    u16* qbf = (u16*)(ws + 0);          // 8 MB (pre-scaled by softmax scale*log2e)
    u16* kbf = (u16*)(ws + 8 * MB);     // 8 MB
    u16* vT  = (u16*)(ws + 16 * MB);    // 8 MB  (n, 1024, 2048)
    u16* ao  = (u16*)(ws + 24 * MB);    // 8 MB  attention out bf16
    u16* hbuf = (u16*)(ws + 0);         // 32 MB (reuses 0..32MB after attention+fc)
    u16* fcwT = (u16*)(ws + 32 * MB);   // 2 MB
    u16* w1T  = (u16*)(ws + 34 * MB);   // 8 MB
    u16* w2T  = (u16*)(ws + 42 * MB);   // 8 MB
    float* attn_raw = (float*)(ws + 50 * MB); // 16 MB
    float* fc_raw   = (float*)(ws + 50 * MB); // reuse (attn_raw dead after LN1)
    float* x1   = (float*)(ws + 66 * MB);     // 16 MB
    u16* x1bf   = (u16*)(ws + 82 * MB);       // 8 MB  (total 90 MB)

    const float k2 = 0.03125f * 1.44269504088896340736f; // 1/sqrt(1024) * log2(e)

    // preprocessing: casts + transposes (bf16, B^T layouts)
    cast_f32_bf16<<<4096, 256, 0, stream>>>(q, qbf, 1048576, k2);
    cast_f32_bf16<<<4096, 256, 0, stream>>>(k, kbf, 1048576, 1.0f);
    transpose_cast<<<dim3(16, 32, 2), 256, 0, stream>>>(v, vT, 2048, 1024);
    transpose_cast<<<dim3(16, 16, 1), 256, 0, stream>>>(fc_w, fcwT, 1024, 1024);
    transpose_cast<<<dim3(64, 16, 1), 256, 0, stream>>>(ff_w1, w1T, 1024, 4096);
    transpose_cast<<<dim3(16, 64, 1), 256, 0, stream>>>(ff_w2, w2T, 4096, 1024);

    // attention (grid 512: 128 q-rows per block, exactly 2 blocks/CU)
    flash_attn<<<512, 256, 0, stream>>>(qbf, kbf, vT, mask, ao);

    // out-proj + LN1  (64x128 tiles -> grid 512 = 2 blocks/CU)
    gemm_bt<64, 128, 0, 0><<<64 * 8, 256, 0, stream>>>(ao, fcwT, fc_b, attn_raw, 4096, 1024, 1024);
    ln_residual<<<4096, 256, 0, stream>>>(attn_raw, q, ln1_g, ln1_b, x1, x1bf);

    // FFN + LN2
    gemm_bt<128, 128, 1, 1><<<32 * 32, 256, 0, stream>>>(x1bf, w1T, ff_b1, hbuf, 4096, 4096, 1024);
    gemm_bt<64, 128, 0, 0><<<64 * 8, 256, 0, stream>>>(hbuf, w2T, ff_b2, fc_raw, 4096, 1024, 4096);
    ln_residual<<<4096, 256, 0, stream>>>(fc_raw, x1, ln2_g, ln2_b, (float*)d_out, (u16*)nullptr);
}

// Round 7
// 431.312 us; speedup vs baseline: 1.6328x; 1.0237x over previous
//
#include <hip/hip_runtime.h>
#include <stdint.h>

typedef unsigned short u16;
typedef __bf16 bf16x8 __attribute__((ext_vector_type(8), may_alias));
typedef float f32x4 __attribute__((ext_vector_type(4), may_alias));

typedef void __attribute__((address_space(1))) as1_void;
typedef void __attribute__((address_space(3))) as3_void;

#define MFMA16 __builtin_amdgcn_mfma_f32_16x16x32_bf16

__device__ __forceinline__ void async_copy16(const void* g, void* l) {
    __builtin_amdgcn_global_load_lds((as1_void*)g, (as3_void*)l, 16, 0, 0);
}

// partial-drain barriers: vmcnt(N) keeps the N newest global loads in flight
// across the sync (AITER-style K-loop; vmcnt returns are in-order per wave).
#define WB0() asm volatile("s_waitcnt vmcnt(0) lgkmcnt(0)\n\ts_barrier" ::: "memory")
#define WB4() asm volatile("s_waitcnt vmcnt(4) lgkmcnt(0)\n\ts_barrier" ::: "memory")
#define WB6() asm volatile("s_waitcnt vmcnt(6) lgkmcnt(0)\n\ts_barrier" ::: "memory")
#define WB8() asm volatile("s_waitcnt vmcnt(8) lgkmcnt(0)\n\ts_barrier" ::: "memory")

// round-to-nearest-even fp32 -> bf16 bits
__device__ __forceinline__ u16 f2bf(float f) {
    union { float f; unsigned u; } c; c.f = f;
    unsigned u = c.u;
    u += 0x7fffu + ((u >> 16) & 1u);
    return (u16)(u >> 16);
}

// ---------------- elementwise cast fp32 -> bf16 (vectorized x4, optional scale) --
__global__ __launch_bounds__(256) void cast_f32_bf16(
    const float* __restrict__ in, u16* __restrict__ out, int n4, float scale) {
    int i = blockIdx.x * 256 + threadIdx.x;
    if (i < n4) {
        f32x4 v = *(const f32x4*)&in[(size_t)i * 4];
        ushort4 o;
        o.x = f2bf(v[0] * scale); o.y = f2bf(v[1] * scale);
        o.z = f2bf(v[2] * scale); o.w = f2bf(v[3] * scale);
        *(ushort4*)&out[(size_t)i * 4] = o;
    }
}

// ---------------- tiled transpose + cast: in fp32 (R,C) -> out bf16 (C,R) -----
__global__ __launch_bounds__(256) void transpose_cast(
    const float* __restrict__ in, u16* __restrict__ out, int R, int C) {
    __shared__ float tile[64][65];
    const float* inb = in + (size_t)blockIdx.z * R * C;
    u16* outb = out + (size_t)blockIdx.z * R * C;
    int t = threadIdx.x;
    int c0 = blockIdx.x * 64, r0 = blockIdx.y * 64;
    int tr = t >> 4, tc = (t & 15) * 4;
#pragma unroll
    for (int p = 0; p < 4; ++p) {
        int r = tr + p * 16;
        f32x4 v = *(const f32x4*)&inb[(size_t)(r0 + r) * C + c0 + tc];
        tile[r][tc] = v[0]; tile[r][tc + 1] = v[1];
        tile[r][tc + 2] = v[2]; tile[r][tc + 3] = v[3];
    }
    __syncthreads();
    int wc = t >> 4, wr = (t & 15) * 4;
#pragma unroll
    for (int p = 0; p < 4; ++p) {
        int cl = wc + p * 16;
        ushort4 o;
        o.x = f2bf(tile[wr + 0][cl]); o.y = f2bf(tile[wr + 1][cl]);
        o.z = f2bf(tile[wr + 2][cl]); o.w = f2bf(tile[wr + 3][cl]);
        *(ushort4*)&outb[(size_t)(c0 + cl) * R + r0 + wr] = o;
    }
}

// ---------------- flash attention v4 (partial-drain barriers) ----------------
// grid 512 = n(2) x h(16) x qt(16); 4 waves, 2 q-tiles/wave.
// B1 = vmcnt(0) (only the 1-iter-old K prefetch outstanding -> cheap);
// V + next-K issued AFTER B1; B2 = vmcnt(4) keeps next-K in flight.
__global__ __launch_bounds__(256) void flash_attn(
    const u16* __restrict__ Q, const u16* __restrict__ Kb,
    const u16* __restrict__ VT, const int* __restrict__ mask,
    u16* __restrict__ O) {
    __shared__ u16 kls[2][8192];   // K tile 128x64, fragment order, double-buffered
    __shared__ u16 vls[8192];      // V^T tile 64x128, fragment order
    __shared__ u16 pls[8][2048];   // per-wave x per-qtile P^T 16x128, XOR-swizzled

    const int bid = blockIdx.x;
    const int qt = bid & 15;
    const int h = (bid >> 4) & 15;
    const int n = bid >> 8;
    const int t = threadIdx.x;
    const int w = t >> 6, lane = t & 63;
    const int m16 = lane & 15, quad = lane >> 4;

    const size_t qrowA = (size_t)(n * 2048 + qt * 128 + w * 16 + m16);
    const size_t qrowB = qrowA + 64;
    bf16x8 qfA0 = *(const bf16x8*)&Q[qrowA * 1024 + h * 64 + quad * 8];
    bf16x8 qfA1 = *(const bf16x8*)&Q[qrowA * 1024 + h * 64 + 32 + quad * 8];
    bf16x8 qfB0 = *(const bf16x8*)&Q[qrowB * 1024 + h * 64 + quad * 8];
    bf16x8 qfB1 = *(const bf16x8*)&Q[qrowB * 1024 + h * 64 + 32 + quad * 8];

    const int* maskn = mask + n * 2048;
    int allones;
    {
        int ok = 1;
#pragma unroll
        for (int i = 0; i < 8; ++i) {
            int4 mv = *(const int4*)&maskn[lane * 32 + i * 4];
            ok &= (mv.x != 0) & (mv.y != 0) & (mv.z != 0) & (mv.w != 0);
        }
        allones = __all(ok);
    }

    f32x4 otA[4] = {}, otB[4] = {};
    f32x4 sumA = {}, sumB = {};

    const u16* Kbase = Kb + (size_t)(n * 2048) * 1024 + h * 64;
    const u16* Vbase = VT + (size_t)(n * 1024 + h * 64) * 2048;
    u16* pwA = &pls[w * 2][0];
    u16* pwB = &pls[w * 2 + 1][0];

    // prologue: stage K tile 0 (drained by iter-0 B1)
#pragma unroll
    for (int i = 0; i < 4; ++i) {
        int e = w * 4 + i;
        async_copy16(&Kbase[(size_t)((e >> 1) * 16 + m16) * 1024 + (e & 1) * 32 + quad * 8],
                     &kls[0][e * 512]);
    }

    for (int kt = 0; kt < 16; ++kt) {
        WB0();   // K(kt) drained (issued 1 iter ago); all waves past PV(kt-1)

        // issue V(kt) first, then K(kt+1): newest 4 = K prefetch
#pragma unroll
        for (int i = 0; i < 4; ++i) {
            int e = w * 4 + i;
            async_copy16(&Vbase[(size_t)((e >> 2) * 16 + m16) * 2048 + kt * 128 +
                                (e & 3) * 32 + quad * 8], &vls[e * 512]);
        }
        if (kt + 1 < 16) {
            u16* knext = kls[(kt + 1) & 1];
#pragma unroll
            for (int i = 0; i < 4; ++i) {
                int e = w * 4 + i;
                async_copy16(&Kbase[(size_t)((kt + 1) * 128 + (e >> 1) * 16 + m16) * 1024 +
                                    (e & 1) * 32 + quad * 8], &knext[e * 512]);
            }
        }

        const u16* kcur = kls[kt & 1];
        f32x4 sA[8] = {}, sB[8] = {};
#pragma unroll
        for (int ct = 0; ct < 8; ++ct) {
            bf16x8 a0 = *(const bf16x8*)&kcur[(ct * 2 + 0) * 512 + lane * 8];
            bf16x8 a1 = *(const bf16x8*)&kcur[(ct * 2 + 1) * 512 + lane * 8];
            sA[ct] = MFMA16(a0, qfA0, sA[ct], 0, 0, 0);
            sA[ct] = MFMA16(a1, qfA1, sA[ct], 0, 0, 0);
            sB[ct] = MFMA16(a0, qfB0, sB[ct], 0, 0, 0);
            sB[ct] = MFMA16(a1, qfB1, sB[ct], 0, 0, 0);
        }

        if (allones) {
#pragma unroll
            for (int ct = 0; ct < 8; ++ct) {
                int c = ct * 2 + (quad >> 1);
                int off = m16 * 128 + (((c ^ m16) & 15) << 3) + (quad & 1) * 4;
                {
                    float p0 = __builtin_amdgcn_exp2f(sA[ct][0]);
                    float p1 = __builtin_amdgcn_exp2f(sA[ct][1]);
                    float p2 = __builtin_amdgcn_exp2f(sA[ct][2]);
                    float p3 = __builtin_amdgcn_exp2f(sA[ct][3]);
                    sumA[0] += p0; sumA[1] += p1; sumA[2] += p2; sumA[3] += p3;
                    unsigned lo = __builtin_amdgcn_perm(__float_as_uint(p1), __float_as_uint(p0), 0x07060302);
                    unsigned hi = __builtin_amdgcn_perm(__float_as_uint(p3), __float_as_uint(p2), 0x07060302);
                    *(uint2*)&pwA[off] = make_uint2(lo, hi);
                }
                {
                    float p0 = __builtin_amdgcn_exp2f(sB[ct][0]);
                    float p1 = __builtin_amdgcn_exp2f(sB[ct][1]);
                    float p2 = __builtin_amdgcn_exp2f(sB[ct][2]);
                    float p3 = __builtin_amdgcn_exp2f(sB[ct][3]);
                    sumB[0] += p0; sumB[1] += p1; sumB[2] += p2; sumB[3] += p3;
                    unsigned lo = __builtin_amdgcn_perm(__float_as_uint(p1), __float_as_uint(p0), 0x07060302);
                    unsigned hi = __builtin_amdgcn_perm(__float_as_uint(p3), __float_as_uint(p2), 0x07060302);
                    *(uint2*)&pwB[off] = make_uint2(lo, hi);
                }
            }
        } else {
#pragma unroll
            for (int ct = 0; ct < 8; ++ct) {
                const int4 mv = *(const int4*)&maskn[kt * 128 + ct * 16 + quad * 4];
                int c = ct * 2 + (quad >> 1);
                int off = m16 * 128 + (((c ^ m16) & 15) << 3) + (quad & 1) * 4;
                {
                    float p0 = __builtin_amdgcn_exp2f(sA[ct][0]) * (mv.x ? 1.f : 0.f);
                    float p1 = __builtin_amdgcn_exp2f(sA[ct][1]) * (mv.y ? 1.f : 0.f);
                    float p2 = __builtin_amdgcn_exp2f(sA[ct][2]) * (mv.z ? 1.f : 0.f);
                    float p3 = __builtin_amdgcn_exp2f(sA[ct][3]) * (mv.w ? 1.f : 0.f);
                    sumA[0] += p0; sumA[1] += p1; sumA[2] += p2; sumA[3] += p3;
                    unsigned lo = __builtin_amdgcn_perm(__float_as_uint(p1), __float_as_uint(p0), 0x07060302);
                    unsigned hi = __builtin_amdgcn_perm(__float_as_uint(p3), __float_as_uint(p2), 0x07060302);
                    *(uint2*)&pwA[off] = make_uint2(lo, hi);
                }
                {
                    float p0 = __builtin_amdgcn_exp2f(sB[ct][0]) * (mv.x ? 1.f : 0.f);
                    float p1 = __builtin_amdgcn_exp2f(sB[ct][1]) * (mv.y ? 1.f : 0.f);
                    float p2 = __builtin_amdgcn_exp2f(sB[ct][2]) * (mv.z ? 1.f : 0.f);
                    float p3 = __builtin_amdgcn_exp2f(sB[ct][3]) * (mv.w ? 1.f : 0.f);
                    sumB[0] += p0; sumB[1] += p1; sumB[2] += p2; sumB[3] += p3;
                    unsigned lo = __builtin_amdgcn_perm(__float_as_uint(p1), __float_as_uint(p0), 0x07060302);
                    unsigned hi = __builtin_amdgcn_perm(__float_as_uint(p3), __float_as_uint(p2), 0x07060302);
                    *(uint2*)&pwB[off] = make_uint2(lo, hi);
                }
            }
        }

        // B2: V(kt) + P in LDS; K(kt+1) (4 newest) stays in flight
        if (kt + 1 < 16) { WB4(); } else { WB0(); }

        bf16x8 pfA[4], pfB[4];
#pragma unroll
        for (int kc2 = 0; kc2 < 4; ++kc2) {
            int off = m16 * 128 + ((((kc2 * 4 + quad) ^ m16) & 15) << 3);
            pfA[kc2] = *(const bf16x8*)&pwA[off];
            pfB[kc2] = *(const bf16x8*)&pwB[off];
        }
#pragma unroll
        for (int kc2 = 0; kc2 < 4; ++kc2) {
#pragma unroll
            for (int dt = 0; dt < 4; ++dt) {
                bf16x8 vf = *(const bf16x8*)&vls[(dt * 4 + kc2) * 512 + lane * 8];
                otA[dt] = MFMA16(vf, pfA[kc2], otA[dt], 0, 0, 0);
                otB[dt] = MFMA16(vf, pfB[kc2], otB[dt], 0, 0, 0);
            }
        }
    }

    float lA = (sumA[0] + sumA[1]) + (sumA[2] + sumA[3]);
    float lB = (sumB[0] + sumB[1]) + (sumB[2] + sumB[3]);
    lA += __shfl_xor(lA, 16); lA += __shfl_xor(lA, 32);
    lB += __shfl_xor(lB, 16); lB += __shfl_xor(lB, 32);
    float invA = 1.f / fmaxf(lA, 1e-30f);
    float invB = 1.f / fmaxf(lB, 1e-30f);

    const size_t obA = qrowA * 1024 + h * 64;
    const size_t obB = qrowB * 1024 + h * 64;
#pragma unroll
    for (int dt = 0; dt < 4; ++dt) {
        unsigned lo = (unsigned)f2bf(otA[dt][0] * invA) | ((unsigned)f2bf(otA[dt][1] * invA) << 16);
        unsigned hi = (unsigned)f2bf(otA[dt][2] * invA) | ((unsigned)f2bf(otA[dt][3] * invA) << 16);
        *(uint2*)&O[obA + dt * 16 + quad * 4] = make_uint2(lo, hi);
        lo = (unsigned)f2bf(otB[dt][0] * invB) | ((unsigned)f2bf(otB[dt][1] * invB) << 16);
        hi = (unsigned)f2bf(otB[dt][2] * invB) | ((unsigned)f2bf(otB[dt][3] * invB) << 16);
        *(uint2*)&O[obB + dt * 16 + quad * 4] = make_uint2(lo, hi);
    }
}

// ---------------- bf16 GEMM v4: 3-stage async pipeline, partial-drain barriers --
// C(M,N) = A(M,K) * Bt(N,K)^T + bias. BM x BN tile, BK=64, 4 waves 2x2.
// Per iter: wait vmcnt(NC) (tile k ready, tile k+1's NC copies stay in flight)
// + barrier; issue tile k+2 into stage (k+2)%3; compute stage k%3.
// Prefetch distance = 2 full iterations. Stage (k+2)%3 was last read at
// compute(k-1), which every wave finished before this barrier.
template <int BM, int BN, int RELU, int OUTBF>
__global__ __launch_bounds__(256) void gemm_bt(
    const u16* __restrict__ A, const u16* __restrict__ Bt,
    const float* __restrict__ bias, void* __restrict__ Cout,
    int M, int N, int K) {
    constexpr int MI = BM / 32;
    constexpr int NJ = BN / 32;
    constexpr int NC = MI + NJ;          // async copies per wave per tile
    constexpr int STG = (BM + BN) * 64;  // u16 per stage
    __shared__ u16 sm[3 * STG];
    const int lane = threadIdx.x & 63;
    const int w = threadIdx.x >> 6;
    const int m16 = lane & 15, quad = lane >> 4;
    const int nBn = N / BN;
    const int bm = blockIdx.x / nBn, bn = blockIdx.x % nBn;
    const int r2 = w >> 1, c2 = w & 1;

    const u16* Abase = A + (size_t)(bm * BM + m16) * K + quad * 8;
    const u16* Bbase = Bt + (size_t)(bn * BN + m16) * K + quad * 8;

    auto issue_tile = [&](int stage, int k0) {
        u16* smA = &sm[stage * STG];
        u16* smB = smA + BM * 64;
#pragma unroll
        for (int i = 0; i < MI; ++i) {
            int e = w * MI + i;
            async_copy16(&Abase[(size_t)((e >> 1) * 16) * K + k0 + (e & 1) * 32], &smA[e * 512]);
        }
#pragma unroll
        for (int i = 0; i < NJ; ++i) {
            int e = w * NJ + i;
            async_copy16(&Bbase[(size_t)((e >> 1) * 16) * K + k0 + (e & 1) * 32], &smB[e * 512]);
        }
    };

    f32x4 acc[MI][NJ] = {};
    const int nK = K >> 6;

    issue_tile(0, 0);
    issue_tile(1, 64);

    int cur = 0;
    for (int kt = 0; kt < nK; ++kt) {
        if (kt + 1 < nK) {
            if constexpr (NC == 6) { WB6(); } else { WB8(); }
        } else {
            WB0();
        }
        if (kt + 2 < nK) {
            int nxt = cur + 2; if (nxt >= 3) nxt -= 3;
            issue_tile(nxt, (kt + 2) << 6);
        }
        const u16* smA = &sm[cur * STG];
        const u16* smB = smA + BM * 64;
#pragma unroll
        for (int kc = 0; kc < 2; ++kc) {
            bf16x8 a[MI], b[NJ];
#pragma unroll
            for (int i = 0; i < MI; ++i)
                a[i] = *(const bf16x8*)&smA[((r2 * MI + i) * 2 + kc) * 512 + lane * 8];
#pragma unroll
            for (int j = 0; j < NJ; ++j)
                b[j] = *(const bf16x8*)&smB[((c2 * NJ + j) * 2 + kc) * 512 + lane * 8];
#pragma unroll
            for (int i = 0; i < MI; ++i)
#pragma unroll
                for (int j = 0; j < NJ; ++j)
                    acc[i][j] = MFMA16(a[i], b[j], acc[i][j], 0, 0, 0);
        }
        cur = (cur == 2) ? 0 : cur + 1;
    }

    // epilogue: D row = quad*4 + reg, col = m16
    float bv[NJ];
#pragma unroll
    for (int j = 0; j < NJ; ++j)
        bv[j] = bias[bn * BN + c2 * (BN / 2) + j * 16 + m16];
#pragma unroll
    for (int i = 0; i < MI; ++i) {
        int row0 = bm * BM + r2 * (BM / 2) + i * 16 + quad * 4;
#pragma unroll
        for (int j = 0; j < NJ; ++j) {
            int col = bn * BN + c2 * (BN / 2) + j * 16 + m16;
#pragma unroll
            for (int r = 0; r < 4; ++r) {
                float v = acc[i][j][r] + bv[j];
                if (RELU) v = fmaxf(v, 0.f);
                size_t idx = (size_t)(row0 + r) * N + col;
                if (OUTBF) ((u16*)Cout)[idx] = f2bf(v);
                else ((float*)Cout)[idx] = v;
            }
        }
    }
}

// ---------------- residual + layernorm (row = 1024) ----------------
__global__ __launch_bounds__(256) void ln_residual(
    const float* __restrict__ x, const float* __restrict__ res,
    const float* __restrict__ g, const float* __restrict__ b,
    float* __restrict__ out_f32, u16* __restrict__ out_bf16) {
    __shared__ float smr[8];
    int row = blockIdx.x;
    int t = threadIdx.x;
    f32x4 xv = *(const f32x4*)&x[(size_t)row * 1024 + t * 4];
    f32x4 rv = *(const f32x4*)&res[(size_t)row * 1024 + t * 4];
    xv += rv;
    float s = xv[0] + xv[1] + xv[2] + xv[3];
    float ss = xv[0] * xv[0] + xv[1] * xv[1] + xv[2] * xv[2] + xv[3] * xv[3];
#pragma unroll
    for (int d = 1; d < 64; d <<= 1) {
        s += __shfl_xor(s, d);
        ss += __shfl_xor(ss, d);
    }
    int w = t >> 6, lane = t & 63;
    if (lane == 0) { smr[w] = s; smr[4 + w] = ss; }
    __syncthreads();
    s = smr[0] + smr[1] + smr[2] + smr[3];
    ss = smr[4] + smr[5] + smr[6] + smr[7];
    float mu = s * (1.f / 1024.f);
    float var = ss * (1.f / 1024.f) - mu * mu;
    float rs = rsqrtf(var + 1e-5f);
    f32x4 gv = *(const f32x4*)&g[t * 4];
    f32x4 bv = *(const f32x4*)&b[t * 4];
    f32x4 y;
#pragma unroll
    for (int i = 0; i < 4; ++i) y[i] = (xv[i] - mu) * rs * gv[i] + bv[i];
    *(f32x4*)&out_f32[(size_t)row * 1024 + t * 4] = y;
    if (out_bf16) {
        ushort4 o;
        o.x = f2bf(y[0]); o.y = f2bf(y[1]); o.z = f2bf(y[2]); o.w = f2bf(y[3]);
        *(ushort4*)&out_bf16[(size_t)row * 1024 + t * 4] = o;
    }
}

extern "C" void kernel_launch(void* const* d_in, const int* in_sizes, int n_in,
                              void* d_out, int out_size, void* d_ws, size_t ws_size,
                              hipStream_t stream) {
    const float* q = (const float*)d_in[0];
    const float* k = (const float*)d_in[1];
    const float* v = (const float*)d_in[2];
    const int* mask = (const int*)d_in[3];
    const float* fc_b = (const float*)d_in[5];
    const float* ln1_g = (const float*)d_in[6];
    const float* ln1_b = (const float*)d_in[7];
    const float* ff_b1 = (const float*)d_in[9];
    const float* ff_b2 = (const float*)d_in[11];
    const float* ln2_g = (const float*)d_in[12];
    const float* ln2_b = (const float*)d_in[13];
    const float* fc_w = (const float*)d_in[4];
    const float* ff_w1 = (const float*)d_in[8];
    const float* ff_w2 = (const float*)d_in[10];

    char* ws = (char*)d_ws;
    const size_t MB = 1024 * 1024;
    u16* qbf = (u16*)(ws + 0);          // 8 MB (pre-scaled by softmax scale*log2e)
    u16* kbf = (u16*)(ws + 8 * MB);     // 8 MB
    u16* vT  = (u16*)(ws + 16 * MB);    // 8 MB  (n, 1024, 2048)
    u16* ao  = (u16*)(ws + 24 * MB);    // 8 MB  attention out bf16
    u16* hbuf = (u16*)(ws + 0);         // 32 MB (reuses 0..32MB after attention+fc)
    u16* fcwT = (u16*)(ws + 32 * MB);   // 2 MB
    u16* w1T  = (u16*)(ws + 34 * MB);   // 8 MB
    u16* w2T  = (u16*)(ws + 42 * MB);   // 8 MB
    float* attn_raw = (float*)(ws + 50 * MB); // 16 MB
    float* fc_raw   = (float*)(ws + 50 * MB); // reuse (attn_raw dead after LN1)
    float* x1   = (float*)(ws + 66 * MB);     // 16 MB
    u16* x1bf   = (u16*)(ws + 82 * MB);       // 8 MB  (total 90 MB)

    const float k2 = 0.03125f * 1.44269504088896340736f; // 1/sqrt(1024) * log2(e)

    // preprocessing: casts + transposes (bf16, B^T layouts)
    cast_f32_bf16<<<4096, 256, 0, stream>>>(q, qbf, 1048576, k2);
    cast_f32_bf16<<<4096, 256, 0, stream>>>(k, kbf, 1048576, 1.0f);
    transpose_cast<<<dim3(16, 32, 2), 256, 0, stream>>>(v, vT, 2048, 1024);
    transpose_cast<<<dim3(16, 16, 1), 256, 0, stream>>>(fc_w, fcwT, 1024, 1024);
    transpose_cast<<<dim3(64, 16, 1), 256, 0, stream>>>(ff_w1, w1T, 1024, 4096);
    transpose_cast<<<dim3(16, 64, 1), 256, 0, stream>>>(ff_w2, w2T, 4096, 1024);

    // attention (grid 512: 128 q-rows per block, exactly 2 blocks/CU)
    flash_attn<<<512, 256, 0, stream>>>(qbf, kbf, vT, mask, ao);

    // out-proj + LN1  (64x128 tiles)
    gemm_bt<64, 128, 0, 0><<<64 * 8, 256, 0, stream>>>(ao, fcwT, fc_b, attn_raw, 4096, 1024, 1024);
    ln_residual<<<4096, 256, 0, stream>>>(attn_raw, q, ln1_g, ln1_b, x1, x1bf);

    // FFN + LN2
    gemm_bt<64, 128, 1, 1><<<64 * 32, 256, 0, stream>>>(x1bf, w1T, ff_b1, hbuf, 4096, 4096, 1024);
    gemm_bt<64, 128, 0, 0><<<64 * 8, 256, 0, stream>>>(hbuf, w2T, ff_b2, fc_raw, 4096, 1024, 4096);
    ln_residual<<<4096, 256, 0, stream>>>(fc_raw, x1, ln2_g, ln2_b, (float*)d_out, (u16*)nullptr);
}